// Round 8
// baseline (263.810 us; speedup 1.0000x reference)
//
#include <hip/hip_runtime.h>

#define KN 12
#define DNBR 320
#define DNEW 256
#define BN_TOT 8192
#define ATB 4                 // atoms per block = waves per block (fused)
#define HATB 16               // atoms per block (h_pre)
#define NKS_E 10              // 320/32
#define NKS_H 8               // 256/32
#define ASTR_H 264            // h_pre A row stride in u16 (256 + 8 pad)
#define H_OFF 294912          // byte offset of precomputed h in workspace (after B2)

typedef short bf8_t __attribute__((ext_vector_type(8)));
typedef float f32x4 __attribute__((ext_vector_type(4)));
typedef unsigned short us8 __attribute__((ext_vector_type(8)));
using u16 = unsigned short;
using u32 = unsigned int;

typedef __attribute__((address_space(3))) void lds_vp;
typedef __attribute__((address_space(1))) const void gc_vp;

__device__ __forceinline__ void dma16(const void* g, void* l) {
    // async global->LDS: 64 lanes x 16B, LDS dest = base + lane*16
    __builtin_amdgcn_global_load_lds((gc_vp*)g, (lds_vp*)l, 16, 0, 0);
}

__device__ __forceinline__ u16 f2bf(float f) {
    u32 x = __float_as_uint(f);
    return (u16)((x + 0x7fffu + ((x >> 16) & 1u)) >> 16);  // RNE
}

__device__ __forceinline__ us8 pack8(float4 a, float4 b) {
    us8 v;
    v[0] = f2bf(a.x); v[1] = f2bf(a.y); v[2] = f2bf(a.z); v[3] = f2bf(a.w);
    v[4] = f2bf(b.x); v[5] = f2bf(b.y); v[6] = f2bf(b.z); v[7] = f2bf(b.w);
    return v;
}

// 8 fp32 -> 8 bf16 via HW packed convert (RNE, bit-identical to f2bf; validated R2)
__device__ __forceinline__ bf8_t cvt8(float4 a, float4 b) {
    u32 r0, r1, r2, r3;
    asm("v_cvt_pk_bf16_f32 %0, %1, %2" : "=v"(r0) : "v"(a.x), "v"(a.y));
    asm("v_cvt_pk_bf16_f32 %0, %1, %2" : "=v"(r1) : "v"(a.z), "v"(a.w));
    asm("v_cvt_pk_bf16_f32 %0, %1, %2" : "=v"(r2) : "v"(b.x), "v"(b.y));
    asm("v_cvt_pk_bf16_f32 %0, %1, %2" : "=v"(r3) : "v"(b.z), "v"(b.w));
    union { u32 u[4]; bf8_t v; } cv;
    cv.u[0] = r0; cv.u[1] = r1; cv.u[2] = r2; cv.u[3] = r3;
    return cv.v;
}

// ---- kernel 1: fragment-major stacked B2: tiles 0..159 = Wn (10 ks x 16 nt),
// tiles 160..287 = Wa (8 ks x 16 nt). Tile = 64 lanes x 8 u16 (1KB). ----
__global__ __launch_bounds__(256) void build_b2(
    const float* __restrict__ Wn, const float* __restrict__ Wa,
    u16* __restrict__ B2)
{
    int tile = blockIdx.x * 4 + (threadIdx.x >> 6);   // 0..287
    int l = threadIdx.x & 63;
    int q = l >> 4, m = l & 15;
    us8 v;
    if (tile < 160) {
        int ks = tile >> 4, nt = tile & 15;
        int col = nt * 16 + m;
#pragma unroll
        for (int e = 0; e < 8; e++)
            v[e] = f2bf(Wn[(ks * 32 + q * 8 + e) * DNEW + col]);
    } else {
        int tt = tile - 160;
        int ks = tt >> 4, nt = tt & 15;
        int col = nt * 16 + m;
#pragma unroll
        for (int e = 0; e < 8; e++)
            v[e] = f2bf(Wa[(ks * 32 + q * 8 + e) * DNEW + col]);
    }
    *(us8*)&B2[(size_t)tile * 512 + l * 8] = v;
}

// ---- kernel 2: precompute h = atomf @ Wa + ba, fp32 to workspace.
// 16 atoms/block (512 blocks: 2/CU), staging loads batched for MLP. ----
__global__ __launch_bounds__(256) void h_pre(
    const float* __restrict__ atomf, const u16* __restrict__ B2,
    const float* __restrict__ ba, float* __restrict__ h_g)
{
    __shared__ u16 A[HATB * ASTR_H];   // 8448 B

    const int t = threadIdx.x;
    const int l = t & 63, w = t >> 6, q = l >> 4, m = l & 15;
    const int ab = blockIdx.x * HATB;

    // stage 16 atoms x 256 f32 -> bf16: 512 us8 chunks, 2/thread, loads batched
    const float* base = atomf + (size_t)ab * DNEW;
    float4 u0 = *(const float4*)(base + t * 8);
    float4 u1 = *(const float4*)(base + t * 8 + 4);
    float4 u2 = *(const float4*)(base + (t + 256) * 8);
    float4 u3 = *(const float4*)(base + (t + 256) * 8 + 4);
    int ai = t >> 5, c8 = t & 31;                 // (t+256)>>5 = ai+8, (t+256)&31 = c8
    *(us8*)&A[ai * ASTR_H + c8 * 8] = pack8(u0, u1);
    *(us8*)&A[(ai + 8) * ASTR_H + c8 * 8] = pack8(u2, u3);
    __syncthreads();

    f32x4 acc[4];
#pragma unroll
    for (int j = 0; j < 4; j++) acc[j] = (f32x4){0.f, 0.f, 0.f, 0.f};

#pragma unroll
    for (int ks = 0; ks < NKS_H; ks++) {
        bf8_t af = *(bf8_t*)&A[m * ASTR_H + ks * 32 + q * 8];
#pragma unroll
        for (int j = 0; j < 4; j++) {
            bf8_t bfj = *(const bf8_t*)&B2[((size_t)(160 + ks * 16 + w * 4 + j) * 64 + l) * 8];
            acc[j] = __builtin_amdgcn_mfma_f32_16x16x32_bf16(af, bfj, acc[j], 0, 0, 0);
        }
    }
#pragma unroll
    for (int j = 0; j < 4; j++) {
        int col = w * 64 + j * 16 + m;
        float bav = ba[col];
#pragma unroll
        for (int r = 0; r < 4; r++) {
            int row = ab + q * 4 + r;
            h_g[(size_t)row * DNEW + col] = acc[j][r] + bav;
        }
    }
}

// ---- kernel 3: fused e-GEMM + GATv2 attention + LN, ZERO BARRIERS.
// One WAVE owns one ATOM end-to-end (all 256 cols, all 8 heads, full LN):
// A2 staging is wave-private (20 coalesced DMA chunks -> 20KB region), drained
// by an OWN-WAVE s_waitcnt vmcnt(0) -- no __syncthreads anywhere, so the 4
// waves (and all 8192 waves grid-wide) slide freely past each other and memory
// latency hides under other waves' compute with no software pipelining needed.
// LDS 80KB -> 2 blocks/CU; launch_bounds(256,2) frees VGPR budget to 256 so
// the 16-tile B2 batch per ks can actually stay in flight. ----
__global__ __launch_bounds__(256, 2) void fused_all(
    const float* __restrict__ nbrf,
    const float* __restrict__ smaskg, const float* __restrict__ amaskg,
    const u16* __restrict__ B2, const float* __restrict__ h_g,
    const float* __restrict__ bnb, const float* __restrict__ walg,
    const float* __restrict__ balg, const float* __restrict__ gam,
    const float* __restrict__ bet, float* __restrict__ out)
{
    __shared__ __align__(16) float smem[ATB * 20 * 256];   // 81920 B = 2 blocks/CU

    const int t = threadIdx.x;
    const int l = t & 63, q = l >> 4, m = l & 15;
    const int w = t >> 6;                          // wave id = atom slot
    const int atom = blockIdx.x * ATB + w;
    const bool qv = (q < 3);

    // ---- coalesced DMA: 20 chunks (10 ks x 2 half-segments) for THIS atom.
    // chunk c: 16 rows (clamped to 12) x one 64B row-segment; lane l=(cc,m)
    // reads row min(m,11), granule cc -> LDS float4 idx cc*16+m (linear dest). ----
    const int cc = l >> 4;                         // granule column 0..3 (== q)
    const int srow = (m < KN) ? m : (KN - 1);      // pad lanes re-read row 11 (masked later)
    const float* abase = nbrf + ((size_t)atom * KN + srow) * DNBR;
    char* lbase = (char*)smem + (size_t)w * 20480; // wave-private 20KB
#pragma unroll
    for (int c = 0; c < 20; c++) {
        int ks = c >> 1, h = c & 1;
        dma16(abase + ks * 32 + h * 16 + cc * 4, lbase + c * 1024);
    }

    // ---- params (in flight together with DMA; covered by the same vmcnt(0)) ----
    const float bal = balg[0];
    float hv[16], bnbv[16];
#pragma unroll
    for (int j = 0; j < 16; j++) {
        int col = j * 16 + m;
        hv[j] = h_g[(size_t)atom * DNEW + col];
        bnbv[j] = bnb[col];
    }
    float wv2[2] = { walg[m], walg[16 + m] };      // head-col (j&1)*16+m
    float smv[4], amv[4];
#pragma unroll
    for (int r = 0; r < 4; r++) {
        int k = q * 4 + r;
        smv[r] = qv ? smaskg[(size_t)atom * KN + k] + bal : 0.f;
        amv[r] = qv ? amaskg[(size_t)atom * KN + k] : 0.f;
    }

    // ---- own-wave drain: this wave's DMA + param loads are complete ----
    asm volatile("s_waitcnt vmcnt(0)" ::: "memory");
    __builtin_amdgcn_sched_barrier(0);

    // ---- e-GEMM: per ks, 16 B2 tile loads (batched, independent) + 1 A-frag ----
    const float4* A2w = (const float4*)lbase;
    const bf8_t* B2v = (const bf8_t*)B2;
    const int aoff = (q & 1) * 32 + m;             // float4 index within chunk
    const int hsel = q >> 1;

    f32x4 acc[16];
#pragma unroll
    for (int j = 0; j < 16; j++) acc[j] = (f32x4){0.f, 0.f, 0.f, 0.f};

#pragma unroll
    for (int ks = 0; ks < NKS_E; ks++) {
        bf8_t bfj[16];
#pragma unroll
        for (int j = 0; j < 16; j++)
            bfj[j] = B2v[(size_t)(ks * 16 + j) * 64 + l];
        float4 lo = A2w[(ks * 2 + hsel) * 64 + aoff];
        float4 hi = A2w[(ks * 2 + hsel) * 64 + aoff + 16];
        bf8_t af = cvt8(lo, hi);
#pragma unroll
        for (int j = 0; j < 16; j++)
            acc[j] = __builtin_amdgcn_mfma_f32_16x16x32_bf16(af, bfj[j], acc[j], 0, 0, 0);
    }

    // ---- e = acc + bnb ----
#pragma unroll
    for (int j = 0; j < 16; j++)
#pragma unroll
        for (int r = 0; r < 4; r++) acc[j][r] += bnbv[j];

    // ---- scores + softmax + attn + ctx + LN partials: ALL wave-local ----
    float ctxv[16];
    float s1 = 0.f, s2 = 0.f;
#pragma unroll
    for (int u = 0; u < 8; u++) {                  // head u: j-tiles 2u, 2u+1
        const int j0 = 2 * u, j1 = 2 * u + 1;
        float p[4];
#pragma unroll
        for (int r = 0; r < 4; r++) {
            float pp = 0.f;
            float f0 = acc[j0][r] + hv[j0];
            f0 = f0 > 0.f ? f0 : 0.01f * f0;
            pp = fmaf(f0, wv2[0], pp);
            float f1 = acc[j1][r] + hv[j1];
            f1 = f1 > 0.f ? f1 : 0.01f * f1;
            pp = fmaf(f1, wv2[1], pp);
            pp += __shfl_xor(pp, 1);
            pp += __shfl_xor(pp, 2);
            pp += __shfl_xor(pp, 4);
            pp += __shfl_xor(pp, 8);
            p[r] = qv ? pp + smv[r] : -1e30f;
        }
        float mx = fmaxf(fmaxf(p[0], p[1]), fmaxf(p[2], p[3]));
        mx = fmaxf(mx, __shfl_xor(mx, 16));
        mx = fmaxf(mx, __shfl_xor(mx, 32));
        float ex[4], ss = 0.f;
#pragma unroll
        for (int r = 0; r < 4; r++) {
            ex[r] = qv ? __expf(p[r] - mx) : 0.f;
            ss += ex[r];
        }
        ss += __shfl_xor(ss, 16);
        ss += __shfl_xor(ss, 32);
        float inv = 1.f / ss;
        float am[4];
#pragma unroll
        for (int r = 0; r < 4; r++)
            am[r] = qv ? ex[r] * inv * amv[r] : 0.f;
#pragma unroll
        for (int jo = 0; jo < 2; jo++) {
            int j = 2 * u + jo;
            float cp = am[0] * acc[j][0] + am[1] * acc[j][1] +
                       am[2] * acc[j][2] + am[3] * acc[j][3];
            cp += __shfl_xor(cp, 16);
            cp += __shfl_xor(cp, 32);
            ctxv[j] = cp;                          // valid in all lanes
            s1 += cp;
            s2 += cp * cp;
        }
    }
    // m-group reduce -> full 256-col sums in every lane
#pragma unroll
    for (int off = 1; off < 16; off <<= 1) {
        s1 += __shfl_xor(s1, off);
        s2 += __shfl_xor(s2, off);
    }
    float mu = s1 * (1.f / 256.f);
    float var = s2 * (1.f / 256.f) - mu * mu;
    var = fmaxf(var, 0.f);
    float rs = rsqrtf(var + 1e-5f);

    // ---- LN epilogue: each q-group stores 4 j-tiles (all 64 lanes active) ----
#pragma unroll
    for (int jj = 0; jj < 4; jj++) {
        int j = q * 4 + jj;
        int col = j * 16 + m;
        out[(size_t)atom * DNEW + col] =
            (ctxv[j] - mu) * rs * gam[col] + bet[col];
    }
}

extern "C" void kernel_launch(void* const* d_in, const int* in_sizes, int n_in,
                              void* d_out, int out_size, void* d_ws, size_t ws_size,
                              hipStream_t stream) {
    const float* atomf = (const float*)d_in[0];
    const float* nbrf  = (const float*)d_in[1];
    const float* smask = (const float*)d_in[2];
    const float* amask = (const float*)d_in[3];
    const float* Wa    = (const float*)d_in[4];
    const float* ba    = (const float*)d_in[5];
    const float* Wn    = (const float*)d_in[6];
    const float* bnb   = (const float*)d_in[7];
    const float* wal   = (const float*)d_in[8];
    const float* bal   = (const float*)d_in[9];
    const float* gam   = (const float*)d_in[10];
    const float* bet   = (const float*)d_in[11];
    float* outp = (float*)d_out;

    u16* B2 = (u16*)d_ws;                              // 288 KiB
    float* h_g = (float*)((char*)d_ws + H_OFF);        // 8 MiB fp32 h

    build_b2<<<72, 256, 0, stream>>>(Wn, Wa, B2);
    h_pre<<<BN_TOT / HATB, 256, 0, stream>>>(atomf, B2, ba, h_g);
    fused_all<<<BN_TOT / ATB, 256, 0, stream>>>(nbrf, smask, amask, B2, h_g,
                                                bnb, wal, bal, gam, bet, outp);
}

// Round 9
// 262.051 us; speedup vs baseline: 1.0067x; 1.0067x over previous
//
#include <hip/hip_runtime.h>

#define KN 12
#define DNBR 320
#define DNEW 256
#define BN_TOT 8192
#define HATB 16               // atoms per block (h_pre)
#define NKS_E 10              // 320/32
#define NKS_H 8               // 256/32
#define ASTR_H 264            // h_pre A row stride in u16 (256 + 8 pad)
#define H_OFF 294912          // byte offset of precomputed h in workspace (after B2)
#define NCHUNK 20             // fused A2 chunks: ks(10) x half(2), 1KB each (1 atom)

typedef short bf8_t __attribute__((ext_vector_type(8)));
typedef float f32x4 __attribute__((ext_vector_type(4)));
typedef unsigned short us8 __attribute__((ext_vector_type(8)));
using u16 = unsigned short;
using u32 = unsigned int;

typedef __attribute__((address_space(3))) void lds_vp;
typedef __attribute__((address_space(1))) const void gc_vp;

__device__ __forceinline__ void dma16(const void* g, void* l) {
    // async global->LDS: 64 lanes x 16B, LDS dest = base + lane*16
    __builtin_amdgcn_global_load_lds((gc_vp*)g, (lds_vp*)l, 16, 0, 0);
}

__device__ __forceinline__ u16 f2bf(float f) {
    u32 x = __float_as_uint(f);
    return (u16)((x + 0x7fffu + ((x >> 16) & 1u)) >> 16);  // RNE
}

__device__ __forceinline__ us8 pack8(float4 a, float4 b) {
    us8 v;
    v[0] = f2bf(a.x); v[1] = f2bf(a.y); v[2] = f2bf(a.z); v[3] = f2bf(a.w);
    v[4] = f2bf(b.x); v[5] = f2bf(b.y); v[6] = f2bf(b.z); v[7] = f2bf(b.w);
    return v;
}

// 8 fp32 -> 8 bf16 via HW packed convert (RNE, bit-identical to f2bf; validated R2)
__device__ __forceinline__ bf8_t cvt8(float4 a, float4 b) {
    u32 r0, r1, r2, r3;
    asm("v_cvt_pk_bf16_f32 %0, %1, %2" : "=v"(r0) : "v"(a.x), "v"(a.y));
    asm("v_cvt_pk_bf16_f32 %0, %1, %2" : "=v"(r1) : "v"(a.z), "v"(a.w));
    asm("v_cvt_pk_bf16_f32 %0, %1, %2" : "=v"(r2) : "v"(b.x), "v"(b.y));
    asm("v_cvt_pk_bf16_f32 %0, %1, %2" : "=v"(r3) : "v"(b.z), "v"(b.w));
    union { u32 u[4]; bf8_t v; } cv;
    cv.u[0] = r0; cv.u[1] = r1; cv.u[2] = r2; cv.u[3] = r3;
    return cv.v;
}

// ---- kernel 1: fragment-major stacked B2: tiles 0..159 = Wn (10 ks x 16 nt),
// tiles 160..287 = Wa (8 ks x 16 nt). Tile = 64 lanes x 8 u16 (1KB). ----
__global__ __launch_bounds__(256) void build_b2(
    const float* __restrict__ Wn, const float* __restrict__ Wa,
    u16* __restrict__ B2)
{
    int tile = blockIdx.x * 4 + (threadIdx.x >> 6);   // 0..287
    int l = threadIdx.x & 63;
    int q = l >> 4, m = l & 15;
    us8 v;
    if (tile < 160) {
        int ks = tile >> 4, nt = tile & 15;
        int col = nt * 16 + m;
#pragma unroll
        for (int e = 0; e < 8; e++)
            v[e] = f2bf(Wn[(ks * 32 + q * 8 + e) * DNEW + col]);
    } else {
        int tt = tile - 160;
        int ks = tt >> 4, nt = tt & 15;
        int col = nt * 16 + m;
#pragma unroll
        for (int e = 0; e < 8; e++)
            v[e] = f2bf(Wa[(ks * 32 + q * 8 + e) * DNEW + col]);
    }
    *(us8*)&B2[(size_t)tile * 512 + l * 8] = v;
}

// ---- kernel 2: precompute h = atomf @ Wa + ba, fp32 to workspace.
// 16 atoms/block (512 blocks: 2/CU), staging loads batched for MLP. ----
__global__ __launch_bounds__(256) void h_pre(
    const float* __restrict__ atomf, const u16* __restrict__ B2,
    const float* __restrict__ ba, float* __restrict__ h_g)
{
    __shared__ u16 A[HATB * ASTR_H];   // 8448 B

    const int t = threadIdx.x;
    const int l = t & 63, w = t >> 6, q = l >> 4, m = l & 15;
    const int ab = blockIdx.x * HATB;

    // stage 16 atoms x 256 f32 -> bf16: 512 us8 chunks, 2/thread, loads batched
    const float* base = atomf + (size_t)ab * DNEW;
    float4 u0 = *(const float4*)(base + t * 8);
    float4 u1 = *(const float4*)(base + t * 8 + 4);
    float4 u2 = *(const float4*)(base + (t + 256) * 8);
    float4 u3 = *(const float4*)(base + (t + 256) * 8 + 4);
    int ai = t >> 5, c8 = t & 31;                 // (t+256)>>5 = ai+8, (t+256)&31 = c8
    *(us8*)&A[ai * ASTR_H + c8 * 8] = pack8(u0, u1);
    *(us8*)&A[(ai + 8) * ASTR_H + c8 * 8] = pack8(u2, u3);
    __syncthreads();

    f32x4 acc[4];
#pragma unroll
    for (int j = 0; j < 4; j++) acc[j] = (f32x4){0.f, 0.f, 0.f, 0.f};

#pragma unroll
    for (int ks = 0; ks < NKS_H; ks++) {
        bf8_t af = *(bf8_t*)&A[m * ASTR_H + ks * 32 + q * 8];
#pragma unroll
        for (int j = 0; j < 4; j++) {
            bf8_t bfj = *(const bf8_t*)&B2[((size_t)(160 + ks * 16 + w * 4 + j) * 64 + l) * 8];
            acc[j] = __builtin_amdgcn_mfma_f32_16x16x32_bf16(af, bfj, acc[j], 0, 0, 0);
        }
    }
#pragma unroll
    for (int j = 0; j < 4; j++) {
        int col = w * 64 + j * 16 + m;
        float bav = ba[col];
#pragma unroll
        for (int r = 0; r < 4; r++) {
            int row = ab + q * 4 + r;
            h_g[(size_t)row * DNEW + col] = acc[j][r] + bav;
        }
    }
}

// ---- kernel 3: fused e-GEMM + GATv2 attention + LN. ONE ATOM PER BLOCK.
// 8192 blocks; LDS = 20 chunks x 1KB = 20480 B -> 8 blocks/CU: 8 independent
// barrier groups per CU (R1-R8 established lockstep-within-block as the
// latency-hiding limiter; blocks/CU is the resource). 4 waves each own 4
// column-tiles (cols w*64..w*64+63). Coalesced DMA: chunk c=(ks,h) covers 16
// rows (clamped to 12) x one contiguous 64B row-segment; lane l=(cc,m) reads
// row min(m,11), granule cc. launch_bounds(256,8) targets the <=64-VGPR tier. ----
__global__ __launch_bounds__(256, 8) void fused_all(
    const float* __restrict__ nbrf,
    const float* __restrict__ smaskg, const float* __restrict__ amaskg,
    const u16* __restrict__ B2, const float* __restrict__ h_g,
    const float* __restrict__ bnb, const float* __restrict__ walg,
    const float* __restrict__ balg, const float* __restrict__ gam,
    const float* __restrict__ bet, float* __restrict__ out)
{
    __shared__ __align__(16) float smem[NCHUNK * 256];   // 20480 B = 8 blocks/CU

    const int t = threadIdx.x;
    const int l = t & 63, w = t >> 6, q = l >> 4, m = l & 15;
    const int atom = blockIdx.x;
    const bool qv = (q < 3);

    // ---- issue async A2 DMA: 20 chunks, wave w takes c = w, w+4, ... ----
    const int cc = l >> 4;                         // granule column 0..3
    const int srow = (m < KN) ? m : (KN - 1);      // pad lanes re-read row 11 (masked later)
    const float* abase = nbrf + ((size_t)atom * KN + srow) * DNBR;
    for (int c = w; c < NCHUNK; c += 4) {
        int ks = c >> 1, h = c & 1;
        dma16(abase + ks * 32 + h * 16 + cc * 4, (char*)smem + (size_t)c * 1024);
    }

    // ---- params (issued before barrier; overlap DMA drain) ----
    const float bal = balg[0];
    float hv[4], bnbv[4], wv[4];
#pragma unroll
    for (int j = 0; j < 4; j++) {
        int col = w * 64 + j * 16 + m;
        hv[j] = h_g[(size_t)atom * DNEW + col];
        bnbv[j] = bnb[col];
        wv[j] = walg[(j * 16 + m) & 31];
    }
    float smv[4], amv[4];
#pragma unroll
    for (int r = 0; r < 4; r++) {
        int k = q * 4 + r;
        smv[r] = qv ? smaskg[(size_t)atom * KN + k] + bal : 0.f;
        amv[r] = qv ? amaskg[(size_t)atom * KN + k] : 0.f;
    }

    __syncthreads();   // b1: DMA drained (vmcnt(0)), A2 ready

    // ---- e-GEMM: per ks, 4 B2 tile loads + 1 A-frag pair + 4 MFMA ----
    const float4* A2 = (const float4*)smem;
    const bf8_t* B2v = (const bf8_t*)B2;
    const int aoff = (q & 1) * 32 + m;             // float4 index within chunk
    const int hsel = q >> 1;

    f32x4 acc[4];
#pragma unroll
    for (int j = 0; j < 4; j++) acc[j] = (f32x4){0.f, 0.f, 0.f, 0.f};

#pragma unroll
    for (int ks = 0; ks < NKS_E; ks++) {
        bf8_t bfj[4];
#pragma unroll
        for (int j = 0; j < 4; j++)
            bfj[j] = B2v[(size_t)(ks * 16 + w * 4 + j) * 64 + l];
        float4 lo = A2[(ks * 2 + hsel) * 64 + aoff];
        float4 hi = A2[(ks * 2 + hsel) * 64 + aoff + 16];
        bf8_t af = cvt8(lo, hi);
#pragma unroll
        for (int j = 0; j < 4; j++)
            acc[j] = __builtin_amdgcn_mfma_f32_16x16x32_bf16(af, bfj[j], acc[j], 0, 0, 0);
    }

    // ---- e = acc + bnb ----
#pragma unroll
    for (int j = 0; j < 4; j++)
#pragma unroll
        for (int r = 0; r < 4; r++) acc[j][r] += bnbv[j];

    // ---- scores + softmax + attn + ctx: wave-local (wave w owns heads 2w,2w+1) ----
    float ctxv[4];
    float s1 = 0.f, s2 = 0.f;
#pragma unroll
    for (int jj = 0; jj < 2; jj++) {
        float p[4];
#pragma unroll
        for (int r = 0; r < 4; r++) {
            float pp = 0.f;
#pragma unroll
            for (int jo = 0; jo < 2; jo++) {
                int j = jj * 2 + jo;
                float f = acc[j][r] + hv[j];
                f = f > 0.f ? f : 0.01f * f;
                pp = fmaf(f, wv[j], pp);
            }
            pp += __shfl_xor(pp, 1);
            pp += __shfl_xor(pp, 2);
            pp += __shfl_xor(pp, 4);
            pp += __shfl_xor(pp, 8);
            p[r] = qv ? pp + smv[r] : -1e30f;
        }
        float mx = fmaxf(fmaxf(p[0], p[1]), fmaxf(p[2], p[3]));
        mx = fmaxf(mx, __shfl_xor(mx, 16));
        mx = fmaxf(mx, __shfl_xor(mx, 32));
        float ex[4], ss = 0.f;
#pragma unroll
        for (int r = 0; r < 4; r++) {
            ex[r] = qv ? __expf(p[r] - mx) : 0.f;
            ss += ex[r];
        }
        ss += __shfl_xor(ss, 16);
        ss += __shfl_xor(ss, 32);
        float inv = 1.f / ss;
        float am[4];
#pragma unroll
        for (int r = 0; r < 4; r++)
            am[r] = qv ? ex[r] * inv * amv[r] : 0.f;
#pragma unroll
        for (int jo = 0; jo < 2; jo++) {
            int j = jj * 2 + jo;
            float cp = am[0] * acc[j][0] + am[1] * acc[j][1] +
                       am[2] * acc[j][2] + am[3] * acc[j][3];
            cp += __shfl_xor(cp, 16);
            cp += __shfl_xor(cp, 32);
            ctxv[j] = cp;
            s1 += cp;
            s2 += cp * cp;
        }
    }
    // m-group reduce -> wave total over its 64 cols
#pragma unroll
    for (int off = 1; off < 16; off <<= 1) {
        s1 += __shfl_xor(s1, off);
        s2 += __shfl_xor(s2, off);
    }

    // ---- LN cross-wave reduce; red_l aliases A2 (dead after K-loop) ----
    float* red_l = smem;   // [8]
    __syncthreads();       // b2: all waves done reading A2
    if (l == 0) { red_l[w] = s1; red_l[4 + w] = s2; }
    __syncthreads();       // b3: red_l visible

    float ts1 = red_l[0] + red_l[1] + red_l[2] + red_l[3];
    float ts2 = red_l[4] + red_l[5] + red_l[6] + red_l[7];
    float mu = ts1 * (1.f / 256.f);
    float var = ts2 * (1.f / 256.f) - mu * mu;
    var = fmaxf(var, 0.f);
    float rs = rsqrtf(var + 1e-5f);
    if (q == 0) {
#pragma unroll
        for (int j = 0; j < 4; j++) {
            int col = w * 64 + j * 16 + m;
            out[(size_t)atom * DNEW + col] =
                (ctxv[j] - mu) * rs * gam[col] + bet[col];
        }
    }
}

extern "C" void kernel_launch(void* const* d_in, const int* in_sizes, int n_in,
                              void* d_out, int out_size, void* d_ws, size_t ws_size,
                              hipStream_t stream) {
    const float* atomf = (const float*)d_in[0];
    const float* nbrf  = (const float*)d_in[1];
    const float* smask = (const float*)d_in[2];
    const float* amask = (const float*)d_in[3];
    const float* Wa    = (const float*)d_in[4];
    const float* ba    = (const float*)d_in[5];
    const float* Wn    = (const float*)d_in[6];
    const float* bnb   = (const float*)d_in[7];
    const float* wal   = (const float*)d_in[8];
    const float* bal   = (const float*)d_in[9];
    const float* gam   = (const float*)d_in[10];
    const float* bet   = (const float*)d_in[11];
    float* outp = (float*)d_out;

    u16* B2 = (u16*)d_ws;                              // 288 KiB
    float* h_g = (float*)((char*)d_ws + H_OFF);        // 8 MiB fp32 h

    build_b2<<<72, 256, 0, stream>>>(Wn, Wa, B2);
    h_pre<<<BN_TOT / HATB, 256, 0, stream>>>(atomf, B2, ba, h_g);
    fused_all<<<BN_TOT, 256, 0, stream>>>(nbrf, smask, amask, B2, h_g,
                                          bnb, wal, bal, gam, bet, outp);
}

// Round 10
// 260.009 us; speedup vs baseline: 1.0146x; 1.0079x over previous
//
#include <hip/hip_runtime.h>

#define KN 12
#define DNBR 320
#define DNEW 256
#define BN_TOT 8192
#define HATB 16               // atoms per block (h_pre)
#define NKS_E 10              // 320/32
#define NKS_H 8               // 256/32
#define ASTR_H 264            // h_pre A row stride in u16 (256 + 8 pad)
#define H_OFF 294912          // byte offset of precomputed h in workspace (after B2)
#define NCHUNK 20             // fused A2 chunks: ks(10) x half(2), 1KB each (1 atom)

typedef short bf8_t __attribute__((ext_vector_type(8)));
typedef float f32x4 __attribute__((ext_vector_type(4)));
typedef unsigned short us8 __attribute__((ext_vector_type(8)));
using u16 = unsigned short;
using u32 = unsigned int;

typedef __attribute__((address_space(3))) void lds_vp;
typedef __attribute__((address_space(1))) const void gc_vp;

__device__ __forceinline__ void dma16(const void* g, void* l) {
    // async global->LDS: 64 lanes x 16B, LDS dest = base + lane*16
    __builtin_amdgcn_global_load_lds((gc_vp*)g, (lds_vp*)l, 16, 0, 0);
}

__device__ __forceinline__ u16 f2bf(float f) {
    u32 x = __float_as_uint(f);
    return (u16)((x + 0x7fffu + ((x >> 16) & 1u)) >> 16);  // RNE
}

__device__ __forceinline__ us8 pack8(float4 a, float4 b) {
    us8 v;
    v[0] = f2bf(a.x); v[1] = f2bf(a.y); v[2] = f2bf(a.z); v[3] = f2bf(a.w);
    v[4] = f2bf(b.x); v[5] = f2bf(b.y); v[6] = f2bf(b.z); v[7] = f2bf(b.w);
    return v;
}

// 8 fp32 -> 8 bf16 via HW packed convert (RNE, bit-identical to f2bf; validated R2)
__device__ __forceinline__ bf8_t cvt8(float4 a, float4 b) {
    u32 r0, r1, r2, r3;
    asm("v_cvt_pk_bf16_f32 %0, %1, %2" : "=v"(r0) : "v"(a.x), "v"(a.y));
    asm("v_cvt_pk_bf16_f32 %0, %1, %2" : "=v"(r1) : "v"(a.z), "v"(a.w));
    asm("v_cvt_pk_bf16_f32 %0, %1, %2" : "=v"(r2) : "v"(b.x), "v"(b.y));
    asm("v_cvt_pk_bf16_f32 %0, %1, %2" : "=v"(r3) : "v"(b.z), "v"(b.w));
    union { u32 u[4]; bf8_t v; } cv;
    cv.u[0] = r0; cv.u[1] = r1; cv.u[2] = r2; cv.u[3] = r3;
    return cv.v;
}

// ---- kernel 1: fragment-major stacked B2: tiles 0..159 = Wn (10 ks x 16 nt),
// tiles 160..287 = Wa (8 ks x 16 nt). Tile = 64 lanes x 8 u16 (1KB). ----
__global__ __launch_bounds__(256) void build_b2(
    const float* __restrict__ Wn, const float* __restrict__ Wa,
    u16* __restrict__ B2)
{
    int tile = blockIdx.x * 4 + (threadIdx.x >> 6);   // 0..287
    int l = threadIdx.x & 63;
    int q = l >> 4, m = l & 15;
    us8 v;
    if (tile < 160) {
        int ks = tile >> 4, nt = tile & 15;
        int col = nt * 16 + m;
#pragma unroll
        for (int e = 0; e < 8; e++)
            v[e] = f2bf(Wn[(ks * 32 + q * 8 + e) * DNEW + col]);
    } else {
        int tt = tile - 160;
        int ks = tt >> 4, nt = tt & 15;
        int col = nt * 16 + m;
#pragma unroll
        for (int e = 0; e < 8; e++)
            v[e] = f2bf(Wa[(ks * 32 + q * 8 + e) * DNEW + col]);
    }
    *(us8*)&B2[(size_t)tile * 512 + l * 8] = v;
}

// ---- kernel 2: precompute h = atomf @ Wa + ba, fp32 to workspace.
// 16 atoms/block (512 blocks: 2/CU), staging loads batched for MLP. ----
__global__ __launch_bounds__(256) void h_pre(
    const float* __restrict__ atomf, const u16* __restrict__ B2,
    const float* __restrict__ ba, float* __restrict__ h_g)
{
    __shared__ u16 A[HATB * ASTR_H];   // 8448 B

    const int t = threadIdx.x;
    const int l = t & 63, w = t >> 6, q = l >> 4, m = l & 15;
    const int ab = blockIdx.x * HATB;

    // stage 16 atoms x 256 f32 -> bf16: 512 us8 chunks, 2/thread, loads batched
    const float* base = atomf + (size_t)ab * DNEW;
    float4 u0 = *(const float4*)(base + t * 8);
    float4 u1 = *(const float4*)(base + t * 8 + 4);
    float4 u2 = *(const float4*)(base + (t + 256) * 8);
    float4 u3 = *(const float4*)(base + (t + 256) * 8 + 4);
    int ai = t >> 5, c8 = t & 31;                 // (t+256)>>5 = ai+8, (t+256)&31 = c8
    *(us8*)&A[ai * ASTR_H + c8 * 8] = pack8(u0, u1);
    *(us8*)&A[(ai + 8) * ASTR_H + c8 * 8] = pack8(u2, u3);
    __syncthreads();

    f32x4 acc[4];
#pragma unroll
    for (int j = 0; j < 4; j++) acc[j] = (f32x4){0.f, 0.f, 0.f, 0.f};

#pragma unroll
    for (int ks = 0; ks < NKS_H; ks++) {
        bf8_t af = *(bf8_t*)&A[m * ASTR_H + ks * 32 + q * 8];
#pragma unroll
        for (int j = 0; j < 4; j++) {
            bf8_t bfj = *(const bf8_t*)&B2[((size_t)(160 + ks * 16 + w * 4 + j) * 64 + l) * 8];
            acc[j] = __builtin_amdgcn_mfma_f32_16x16x32_bf16(af, bfj, acc[j], 0, 0, 0);
        }
    }
#pragma unroll
    for (int j = 0; j < 4; j++) {
        int col = w * 64 + j * 16 + m;
        float bav = ba[col];
#pragma unroll
        for (int r = 0; r < 4; r++) {
            int row = ab + q * 4 + r;
            h_g[(size_t)row * DNEW + col] = acc[j][r] + bav;
        }
    }
}

// ---- kernel 3: fused e-GEMM + GATv2 attention + LN. ONE ATOM PER BLOCK.
// 8192 blocks; LDS = 20 chunks x 1KB = 20480 B. launch_bounds(256,6): VGPR cap
// 84 (no spill -- R9's (256,8) forced VGPR=32 + 16MB scratch spill, poisoning
// the occupancy experiment). blocks/CU = min(LDS:8, waves:6) = 6 independent
// barrier groups, 24 waves/CU (~75%). 4 waves each own 4 column-tiles.
// Coalesced DMA: chunk c=(ks,h) covers 16 rows (clamped to 12) x one contiguous
// 64B row-segment; lane l=(cc,m) reads row min(m,11), granule cc. ----
__global__ __launch_bounds__(256, 6) void fused_all(
    const float* __restrict__ nbrf,
    const float* __restrict__ smaskg, const float* __restrict__ amaskg,
    const u16* __restrict__ B2, const float* __restrict__ h_g,
    const float* __restrict__ bnb, const float* __restrict__ walg,
    const float* __restrict__ balg, const float* __restrict__ gam,
    const float* __restrict__ bet, float* __restrict__ out)
{
    __shared__ __align__(16) float smem[NCHUNK * 256];   // 20480 B

    const int t = threadIdx.x;
    const int l = t & 63, w = t >> 6, q = l >> 4, m = l & 15;
    const int atom = blockIdx.x;
    const bool qv = (q < 3);

    // ---- issue async A2 DMA: 20 chunks, wave w takes c = w, w+4, ... ----
    const int cc = l >> 4;                         // granule column 0..3
    const int srow = (m < KN) ? m : (KN - 1);      // pad lanes re-read row 11 (masked later)
    const float* abase = nbrf + ((size_t)atom * KN + srow) * DNBR;
    for (int c = w; c < NCHUNK; c += 4) {
        int ks = c >> 1, h = c & 1;
        dma16(abase + ks * 32 + h * 16 + cc * 4, (char*)smem + (size_t)c * 1024);
    }

    // ---- params (issued before barrier; overlap DMA drain) ----
    const float bal = balg[0];
    float hv[4], bnbv[4], wv[4];
#pragma unroll
    for (int j = 0; j < 4; j++) {
        int col = w * 64 + j * 16 + m;
        hv[j] = h_g[(size_t)atom * DNEW + col];
        bnbv[j] = bnb[col];
        wv[j] = walg[(j * 16 + m) & 31];
    }
    float smv[4], amv[4];
#pragma unroll
    for (int r = 0; r < 4; r++) {
        int k = q * 4 + r;
        smv[r] = qv ? smaskg[(size_t)atom * KN + k] + bal : 0.f;
        amv[r] = qv ? amaskg[(size_t)atom * KN + k] : 0.f;
    }

    __syncthreads();   // b1: DMA drained (vmcnt(0)), A2 ready

    // ---- e-GEMM: per ks, 4 B2 tile loads + 1 A-frag pair + 4 MFMA ----
    const float4* A2 = (const float4*)smem;
    const bf8_t* B2v = (const bf8_t*)B2;
    const int aoff = (q & 1) * 32 + m;             // float4 index within chunk
    const int hsel = q >> 1;

    f32x4 acc[4];
#pragma unroll
    for (int j = 0; j < 4; j++) acc[j] = (f32x4){0.f, 0.f, 0.f, 0.f};

#pragma unroll
    for (int ks = 0; ks < NKS_E; ks++) {
        bf8_t bfj[4];
#pragma unroll
        for (int j = 0; j < 4; j++)
            bfj[j] = B2v[(size_t)(ks * 16 + w * 4 + j) * 64 + l];
        float4 lo = A2[(ks * 2 + hsel) * 64 + aoff];
        float4 hi = A2[(ks * 2 + hsel) * 64 + aoff + 16];
        bf8_t af = cvt8(lo, hi);
#pragma unroll
        for (int j = 0; j < 4; j++)
            acc[j] = __builtin_amdgcn_mfma_f32_16x16x32_bf16(af, bfj[j], acc[j], 0, 0, 0);
    }

    // ---- e = acc + bnb ----
#pragma unroll
    for (int j = 0; j < 4; j++)
#pragma unroll
        for (int r = 0; r < 4; r++) acc[j][r] += bnbv[j];

    // ---- scores + softmax + attn + ctx: wave-local (wave w owns heads 2w,2w+1) ----
    float ctxv[4];
    float s1 = 0.f, s2 = 0.f;
#pragma unroll
    for (int jj = 0; jj < 2; jj++) {
        float p[4];
#pragma unroll
        for (int r = 0; r < 4; r++) {
            float pp = 0.f;
#pragma unroll
            for (int jo = 0; jo < 2; jo++) {
                int j = jj * 2 + jo;
                float f = acc[j][r] + hv[j];
                f = f > 0.f ? f : 0.01f * f;
                pp = fmaf(f, wv[j], pp);
            }
            pp += __shfl_xor(pp, 1);
            pp += __shfl_xor(pp, 2);
            pp += __shfl_xor(pp, 4);
            pp += __shfl_xor(pp, 8);
            p[r] = qv ? pp + smv[r] : -1e30f;
        }
        float mx = fmaxf(fmaxf(p[0], p[1]), fmaxf(p[2], p[3]));
        mx = fmaxf(mx, __shfl_xor(mx, 16));
        mx = fmaxf(mx, __shfl_xor(mx, 32));
        float ex[4], ss = 0.f;
#pragma unroll
        for (int r = 0; r < 4; r++) {
            ex[r] = qv ? __expf(p[r] - mx) : 0.f;
            ss += ex[r];
        }
        ss += __shfl_xor(ss, 16);
        ss += __shfl_xor(ss, 32);
        float inv = 1.f / ss;
        float am[4];
#pragma unroll
        for (int r = 0; r < 4; r++)
            am[r] = qv ? ex[r] * inv * amv[r] : 0.f;
#pragma unroll
        for (int jo = 0; jo < 2; jo++) {
            int j = jj * 2 + jo;
            float cp = am[0] * acc[j][0] + am[1] * acc[j][1] +
                       am[2] * acc[j][2] + am[3] * acc[j][3];
            cp += __shfl_xor(cp, 16);
            cp += __shfl_xor(cp, 32);
            ctxv[j] = cp;
            s1 += cp;
            s2 += cp * cp;
        }
    }
    // m-group reduce -> wave total over its 64 cols
#pragma unroll
    for (int off = 1; off < 16; off <<= 1) {
        s1 += __shfl_xor(s1, off);
        s2 += __shfl_xor(s2, off);
    }

    // ---- LN cross-wave reduce; red_l aliases A2 (dead after K-loop) ----
    float* red_l = smem;   // [8]
    __syncthreads();       // b2: all waves done reading A2
    if (l == 0) { red_l[w] = s1; red_l[4 + w] = s2; }
    __syncthreads();       // b3: red_l visible

    float ts1 = red_l[0] + red_l[1] + red_l[2] + red_l[3];
    float ts2 = red_l[4] + red_l[5] + red_l[6] + red_l[7];
    float mu = ts1 * (1.f / 256.f);
    float var = ts2 * (1.f / 256.f) - mu * mu;
    var = fmaxf(var, 0.f);
    float rs = rsqrtf(var + 1e-5f);
    if (q == 0) {
#pragma unroll
        for (int j = 0; j < 4; j++) {
            int col = w * 64 + j * 16 + m;
            out[(size_t)atom * DNEW + col] =
                (ctxv[j] - mu) * rs * gam[col] + bet[col];
        }
    }
}

extern "C" void kernel_launch(void* const* d_in, const int* in_sizes, int n_in,
                              void* d_out, int out_size, void* d_ws, size_t ws_size,
                              hipStream_t stream) {
    const float* atomf = (const float*)d_in[0];
    const float* nbrf  = (const float*)d_in[1];
    const float* smask = (const float*)d_in[2];
    const float* amask = (const float*)d_in[3];
    const float* Wa    = (const float*)d_in[4];
    const float* ba    = (const float*)d_in[5];
    const float* Wn    = (const float*)d_in[6];
    const float* bnb   = (const float*)d_in[7];
    const float* wal   = (const float*)d_in[8];
    const float* bal   = (const float*)d_in[9];
    const float* gam   = (const float*)d_in[10];
    const float* bet   = (const float*)d_in[11];
    float* outp = (float*)d_out;

    u16* B2 = (u16*)d_ws;                              // 288 KiB
    float* h_g = (float*)((char*)d_ws + H_OFF);        // 8 MiB fp32 h

    build_b2<<<72, 256, 0, stream>>>(Wn, Wa, B2);
    h_pre<<<BN_TOT / HATB, 256, 0, stream>>>(atomf, B2, ba, h_g);
    fused_all<<<BN_TOT, 256, 0, stream>>>(nbrf, smask, amask, B2, h_g,
                                          bnb, wal, bal, gam, bet, outp);
}

// Round 11
// 249.743 us; speedup vs baseline: 1.0563x; 1.0411x over previous
//
#include <hip/hip_runtime.h>

#define KN 12
#define DNBR 320
#define DNEW 256
#define BN_TOT 8192
#define ATB 2                 // atoms per block (fused)
#define HATB 16               // atoms per block (h_pre part of prelude)
#define NB2 40                // prelude blocks doing B2-Wn tiles (160 tiles / 4)
#define NKS_E 10              // 320/32
#define NKS_H 8               // 256/32
#define ASTR_H 264            // prelude A row stride in u16 (256 + 8 pad)
#define H_OFF 294912          // byte offset of precomputed h in workspace
#define NCHUNK 40             // fused A2 chunks: at(2) x ks(10) x half(2), 1KB each
#define PFK 3                 // B2 ks-slices preloaded before the barrier

typedef short bf8_t __attribute__((ext_vector_type(8)));
typedef float f32x4 __attribute__((ext_vector_type(4)));
typedef unsigned short us8 __attribute__((ext_vector_type(8)));
using u16 = unsigned short;
using u32 = unsigned int;

typedef __attribute__((address_space(3))) void lds_vp;
typedef __attribute__((address_space(1))) const void gc_vp;

__device__ __forceinline__ void dma16(const void* g, void* l) {
    // async global->LDS: 64 lanes x 16B, LDS dest = base + lane*16
    __builtin_amdgcn_global_load_lds((gc_vp*)g, (lds_vp*)l, 16, 0, 0);
}

__device__ __forceinline__ u16 f2bf(float f) {
    u32 x = __float_as_uint(f);
    return (u16)((x + 0x7fffu + ((x >> 16) & 1u)) >> 16);  // RNE
}

__device__ __forceinline__ us8 pack8(float4 a, float4 b) {
    us8 v;
    v[0] = f2bf(a.x); v[1] = f2bf(a.y); v[2] = f2bf(a.z); v[3] = f2bf(a.w);
    v[4] = f2bf(b.x); v[5] = f2bf(b.y); v[6] = f2bf(b.z); v[7] = f2bf(b.w);
    return v;
}

// 8 fp32 -> 8 bf16 via HW packed convert (RNE, bit-identical to f2bf; validated R2)
__device__ __forceinline__ bf8_t cvt8(float4 a, float4 b) {
    u32 r0, r1, r2, r3;
    asm("v_cvt_pk_bf16_f32 %0, %1, %2" : "=v"(r0) : "v"(a.x), "v"(a.y));
    asm("v_cvt_pk_bf16_f32 %0, %1, %2" : "=v"(r1) : "v"(a.z), "v"(a.w));
    asm("v_cvt_pk_bf16_f32 %0, %1, %2" : "=v"(r2) : "v"(b.x), "v"(b.y));
    asm("v_cvt_pk_bf16_f32 %0, %1, %2" : "=v"(r3) : "v"(b.z), "v"(b.w));
    union { u32 u[4]; bf8_t v; } cv;
    cv.u[0] = r0; cv.u[1] = r1; cv.u[2] = r2; cv.u[3] = r3;
    return cv.v;
}

// ---- kernel 1: MERGED prelude (one dispatch, no internal dependency).
// Blocks 0..39: build B2-Wn tiles 0..159 (fragment-major, tile = 1KB).
// Blocks 40..551: h_pre = atomf @ Wa + ba -> fp32 h_g. Wa fragments are
// gathered DIRECTLY from fp32 Wa (lane(q,m) elem e reads
// Wa[(ks*32+q*8+e)*256+col]: 16 contiguous lanes = 64B segments) and packed
// with bit-exact cvt_pk -- no dependency on the B2 builder blocks. ----
__global__ __launch_bounds__(256) void prelude(
    const float* __restrict__ Wn, const float* __restrict__ Wa,
    const float* __restrict__ atomf, const float* __restrict__ ba,
    u16* __restrict__ B2, float* __restrict__ h_g)
{
    __shared__ u16 A[HATB * ASTR_H];   // 8448 B (h-path only)

    const int t = threadIdx.x;
    const int l = t & 63, w = t >> 6, q = l >> 4, m = l & 15;

    if (blockIdx.x < NB2) {
        // ---- B2-Wn tiles: 4 tiles/block, tile = 64 lanes x 8 u16 ----
        int tile = blockIdx.x * 4 + w;             // 0..159
        int ks = tile >> 4, nt = tile & 15;
        int col = nt * 16 + m;
        us8 v;
#pragma unroll
        for (int e = 0; e < 8; e++)
            v[e] = f2bf(Wn[(ks * 32 + q * 8 + e) * DNEW + col]);
        *(us8*)&B2[(size_t)tile * 512 + l * 8] = v;
        return;
    }

    // ---- h_pre: 16 atoms/block ----
    const int ab = (blockIdx.x - NB2) * HATB;

    // stage 16 atoms x 256 f32 -> bf16: 512 us8 chunks, 2/thread, loads batched
    const float* base = atomf + (size_t)ab * DNEW;
    float4 u0 = *(const float4*)(base + t * 8);
    float4 u1 = *(const float4*)(base + t * 8 + 4);
    float4 u2 = *(const float4*)(base + (t + 256) * 8);
    float4 u3 = *(const float4*)(base + (t + 256) * 8 + 4);
    int ai = t >> 5, c8 = t & 31;
    *(us8*)&A[ai * ASTR_H + c8 * 8] = pack8(u0, u1);
    *(us8*)&A[(ai + 8) * ASTR_H + c8 * 8] = pack8(u2, u3);
    __syncthreads();

    f32x4 acc[4];
#pragma unroll
    for (int j = 0; j < 4; j++) acc[j] = (f32x4){0.f, 0.f, 0.f, 0.f};

#pragma unroll
    for (int ks = 0; ks < NKS_H; ks++) {
        bf8_t af = *(bf8_t*)&A[m * ASTR_H + ks * 32 + q * 8];
#pragma unroll
        for (int j = 0; j < 4; j++) {
            int colb = (w * 4 + j) * 16 + m;
            float fe[8];
#pragma unroll
            for (int e = 0; e < 8; e++)
                fe[e] = Wa[(size_t)(ks * 32 + q * 8 + e) * DNEW + colb];
            bf8_t bfj = cvt8(make_float4(fe[0], fe[1], fe[2], fe[3]),
                             make_float4(fe[4], fe[5], fe[6], fe[7]));
            acc[j] = __builtin_amdgcn_mfma_f32_16x16x32_bf16(af, bfj, acc[j], 0, 0, 0);
        }
    }
#pragma unroll
    for (int j = 0; j < 4; j++) {
        int col = w * 64 + j * 16 + m;
        float bav = ba[col];
#pragma unroll
        for (int r = 0; r < 4; r++) {
            int row = ab + q * 4 + r;
            h_g[(size_t)row * DNEW + col] = acc[j][r] + bav;
        }
    }
}

// ---- kernel 2: fused e-GEMM + GATv2 attention + LN. 2 atoms/block.
// VERBATIM R7 (best measured: 87.6 us). Coalesced DMA: chunk c=(at,ks,h)
// covers 16 rows (clamped to 12) x one contiguous 64B row-segment; lane
// l=(cc,m) reads row min(m,11), granule cc. B2 preload (PFK=3) pinned by the
// barrier. K-loop: 4 B2 tile loads + 2 A-frag ds_reads + cvt + 8 MFMA per ks. ----
__global__ __launch_bounds__(256, 4) void fused_all(
    const float* __restrict__ nbrf,
    const float* __restrict__ smaskg, const float* __restrict__ amaskg,
    const u16* __restrict__ B2, const float* __restrict__ h_g,
    const float* __restrict__ bnb, const float* __restrict__ walg,
    const float* __restrict__ balg, const float* __restrict__ gam,
    const float* __restrict__ bet, float* __restrict__ out)
{
    __shared__ __align__(16) float smem[NCHUNK * 256];   // 40960 B = 4 blocks/CU

    const int t = threadIdx.x;
    const int l = t & 63, w = t >> 6, q = l >> 4, m = l & 15;
    const int a0 = blockIdx.x * ATB;
    const bool qv = (q < 3);
    const bf8_t* B2v = (const bf8_t*)B2;

    // ---- B2 preload: pinned by the barrier (cannot be sunk past it) ----
    bf8_t pf[PFK][4];
#pragma unroll
    for (int ks = 0; ks < PFK; ks++)
#pragma unroll
        for (int j = 0; j < 4; j++)
            pf[ks][j] = B2v[(size_t)(ks * 16 + w * 4 + j) * 64 + l];

    // ---- issue async A2 DMA: 40 chunks, wave w takes c = w, w+4, ... ----
    const int cc = l >> 4;                      // granule column 0..3
    const int srow = (m < KN) ? m : (KN - 1);   // clamp: pad lanes re-read row 11 (masked later)
    for (int c = w; c < NCHUNK; c += 4) {
        int at = c / 20, rem = c - at * 20, ks = rem >> 1, h = rem & 1;
        const float* src = nbrf + ((size_t)(a0 + at) * KN + srow) * DNBR
                         + ks * 32 + h * 16 + cc * 4;
        dma16(src, (char*)smem + (size_t)c * 1024);
    }

    // ---- params (issued before barrier; overlap DMA drain) ----
    const float bal = balg[0];
    float hv[ATB][4], bnbv[4], wv[4];
#pragma unroll
    for (int j = 0; j < 4; j++) {
        int col = w * 64 + j * 16 + m;
        hv[0][j] = h_g[(size_t)(a0 + 0) * DNEW + col];
        hv[1][j] = h_g[(size_t)(a0 + 1) * DNEW + col];
        bnbv[j] = bnb[col];
        wv[j] = walg[(j * 16 + m) & 31];
    }
    float smv[ATB][4], amv[ATB][4];
#pragma unroll
    for (int at = 0; at < ATB; at++)
#pragma unroll
        for (int r = 0; r < 4; r++) {
            int k = q * 4 + r;
            smv[at][r] = qv ? smaskg[(size_t)(a0 + at) * KN + k] + bal : 0.f;
            amv[at][r] = qv ? amaskg[(size_t)(a0 + at) * KN + k] : 0.f;
        }

    __syncthreads();   // b1: DMA + preloads drained (vmcnt(0)), A2 ready

    // ---- e-GEMM ----
    const float4* A2 = (const float4*)smem;
    const int aoff = (q & 1) * 32 + m;          // float4 index within chunk
    const int hsel = q >> 1;

    f32x4 acc_e[ATB][4];
#pragma unroll
    for (int at = 0; at < ATB; at++)
#pragma unroll
        for (int j = 0; j < 4; j++) acc_e[at][j] = (f32x4){0.f, 0.f, 0.f, 0.f};

#pragma unroll
    for (int ks = 0; ks < NKS_E; ks++) {
        bf8_t bfj[4];
        if (ks < PFK) {
#pragma unroll
            for (int j = 0; j < 4; j++) bfj[j] = pf[ks][j];
        } else {
#pragma unroll
            for (int j = 0; j < 4; j++)
                bfj[j] = B2v[(size_t)(ks * 16 + w * 4 + j) * 64 + l];
        }
        int c0 = ((0 * NKS_E + ks) * 2 + hsel) * 64 + aoff;
        int c1 = ((1 * NKS_E + ks) * 2 + hsel) * 64 + aoff;
        float4 lo0 = A2[c0], hi0 = A2[c0 + 16];
        float4 lo1 = A2[c1], hi1 = A2[c1 + 16];
        bf8_t af0 = cvt8(lo0, hi0);
        bf8_t af1 = cvt8(lo1, hi1);
#pragma unroll
        for (int j = 0; j < 4; j++) {
            acc_e[0][j] = __builtin_amdgcn_mfma_f32_16x16x32_bf16(af0, bfj[j], acc_e[0][j], 0, 0, 0);
            acc_e[1][j] = __builtin_amdgcn_mfma_f32_16x16x32_bf16(af1, bfj[j], acc_e[1][j], 0, 0, 0);
        }
    }

    // ---- e_reg = acc_e + bnb (true e) ----
#pragma unroll
    for (int j = 0; j < 4; j++) {
#pragma unroll
        for (int at = 0; at < ATB; at++)
#pragma unroll
            for (int r = 0; r < 4; r++) acc_e[at][j][r] += bnbv[j];
    }

    // ---- scores + softmax + attn + ctx: wave-local (wave w owns heads 2w,2w+1) ----
    float ctxv[ATB][4], s1s[ATB], s2s[ATB];
#pragma unroll
    for (int at = 0; at < ATB; at++) {
        float s1 = 0.f, s2 = 0.f;
#pragma unroll
        for (int jj = 0; jj < 2; jj++) {
            float p[4];
#pragma unroll
            for (int r = 0; r < 4; r++) {
                float pp = 0.f;
#pragma unroll
                for (int jo = 0; jo < 2; jo++) {
                    int j = jj * 2 + jo;
                    float f = acc_e[at][j][r] + hv[at][j];
                    f = f > 0.f ? f : 0.01f * f;
                    pp = fmaf(f, wv[j], pp);
                }
                pp += __shfl_xor(pp, 1);
                pp += __shfl_xor(pp, 2);
                pp += __shfl_xor(pp, 4);
                pp += __shfl_xor(pp, 8);
                p[r] = qv ? pp + smv[at][r] : -1e30f;
            }
            float mx = fmaxf(fmaxf(p[0], p[1]), fmaxf(p[2], p[3]));
            mx = fmaxf(mx, __shfl_xor(mx, 16));
            mx = fmaxf(mx, __shfl_xor(mx, 32));
            float ex[4], ss = 0.f;
#pragma unroll
            for (int r = 0; r < 4; r++) {
                ex[r] = qv ? __expf(p[r] - mx) : 0.f;
                ss += ex[r];
            }
            ss += __shfl_xor(ss, 16);
            ss += __shfl_xor(ss, 32);
            float inv = 1.f / ss;
            float am[4];
#pragma unroll
            for (int r = 0; r < 4; r++)
                am[r] = qv ? ex[r] * inv * amv[at][r] : 0.f;
#pragma unroll
            for (int jo = 0; jo < 2; jo++) {
                int j = jj * 2 + jo;
                float cp = am[0] * acc_e[at][j][0] + am[1] * acc_e[at][j][1] +
                           am[2] * acc_e[at][j][2] + am[3] * acc_e[at][j][3];
                cp += __shfl_xor(cp, 16);
                cp += __shfl_xor(cp, 32);
                ctxv[at][j] = cp;
                s1 += cp;
                s2 += cp * cp;
            }
        }
#pragma unroll
        for (int off = 1; off < 16; off <<= 1) {
            s1 += __shfl_xor(s1, off);
            s2 += __shfl_xor(s2, off);
        }
        s1s[at] = s1; s2s[at] = s2;
    }

    // ---- LN cross-wave reduce; red_l aliases A2 (dead after K-loop) ----
    float* red_l = smem;   // [ATB][8]
    __syncthreads();       // b2: all waves done reading A2
    if (l == 0) {
#pragma unroll
        for (int at = 0; at < ATB; at++) {
            red_l[at * 8 + w] = s1s[at];
            red_l[at * 8 + 4 + w] = s2s[at];
        }
    }
    __syncthreads();       // b3: red_l visible

    // ---- LayerNorm epilogue ----
#pragma unroll
    for (int at = 0; at < ATB; at++) {
        float ts1 = red_l[at * 8 + 0] + red_l[at * 8 + 1] + red_l[at * 8 + 2] + red_l[at * 8 + 3];
        float ts2 = red_l[at * 8 + 4] + red_l[at * 8 + 5] + red_l[at * 8 + 6] + red_l[at * 8 + 7];
        float mu = ts1 * (1.f / 256.f);
        float var = ts2 * (1.f / 256.f) - mu * mu;
        var = fmaxf(var, 0.f);
        float rs = rsqrtf(var + 1e-5f);
        if (q == 0) {
#pragma unroll
            for (int j = 0; j < 4; j++) {
                int col = w * 64 + j * 16 + m;
                out[(size_t)(a0 + at) * DNEW + col] =
                    (ctxv[at][j] - mu) * rs * gam[col] + bet[col];
            }
        }
    }
}

extern "C" void kernel_launch(void* const* d_in, const int* in_sizes, int n_in,
                              void* d_out, int out_size, void* d_ws, size_t ws_size,
                              hipStream_t stream) {
    const float* atomf = (const float*)d_in[0];
    const float* nbrf  = (const float*)d_in[1];
    const float* smask = (const float*)d_in[2];
    const float* amask = (const float*)d_in[3];
    const float* Wa    = (const float*)d_in[4];
    const float* ba    = (const float*)d_in[5];
    const float* Wn    = (const float*)d_in[6];
    const float* bnb   = (const float*)d_in[7];
    const float* wal   = (const float*)d_in[8];
    const float* bal   = (const float*)d_in[9];
    const float* gam   = (const float*)d_in[10];
    const float* bet   = (const float*)d_in[11];
    float* outp = (float*)d_out;

    u16* B2 = (u16*)d_ws;                              // 160 KiB (Wn tiles only)
    float* h_g = (float*)((char*)d_ws + H_OFF);        // 8 MiB fp32 h

    prelude<<<NB2 + BN_TOT / HATB, 256, 0, stream>>>(Wn, Wa, atomf, ba, B2, h_g);
    fused_all<<<BN_TOT / ATB, 256, 0, stream>>>(nbrf, smask, amask, B2, h_g,
                                                bnb, wal, bal, gam, bet, outp);
}